// Round 3
// baseline (263.038 us; speedup 1.0000x reference)
//
#include <hip/hip_runtime.h>
#include <math.h>

// Problem constants (reference: x_l [16, 1, 1536, 1536] fp32, PATCH=3, ALPHA=1)
#define IMG_W 1536
#define IMG_H 1536
#define NIMG  16
#define RPB   32                    // output rows per block (streaming)
#define NROWS (RPB + 2)             // processed rows incl. vertical halo
#define PF    6                     // prefetch depth (rows in flight per wave)

typedef float f32x4 __attribute__((ext_vector_type(4)));

// out(h,w) = sum_k v_k*exp(-v_k) / sum_k exp(-v_k) over the 3x3 zero-padded
// neighborhood (the "-x^2" shift cancels in softmax; padded taps: e=1, ve=0).
//
// R7 = R6 re-run (round 2 bench was an infra failure, kernel never executed).
// R6 change vs R5: the burst-load wave shape kept loads outstanding for only
// a tiny slice of each wave's ~16us life -> latency-bound at ~2.8 TB/s while
// the harness memsets hit 6.7 TB/s on the same buffers. This version streams:
// each block owns a 512x32 stripe; every unrolled iteration issues row i+PF's
// loads, computes row i's horizontal 3-sums, and stores output row i-2 from
// the rolling vertical window -> loads are in flight for ~100% of wave life.
// Body is fully branchless (clamped row addresses + value selects; halo via
// clamped byte offsets) so each iteration is one scheduling region with a
// single sched_barrier(0) pinning "issue before compute".
__global__ __launch_bounds__(128)
void WeightedAverage_55551107006568_kernel(const float* __restrict__ x,
                                           float* __restrict__ out) {
    const int g  = blockIdx.x * 128 + threadIdx.x;   // column-group index
    const int w0 = g << 2;                           // first owned column
    const int h0 = blockIdx.y * RPB;
    const size_t plane = (size_t)blockIdx.z * ((size_t)IMG_H * IMG_W);
    const float* xp = x + plane;
    float* op = out + plane;

    const bool lok = (w0 > 0);            // col w0-1 exists (false only for g==0)
    const bool rok = (w0 + 4 < IMG_W);    // col w0+4 exists (false only for last g)
    // Safe, branchless halo addressing: out-of-image halo reads are redirected
    // to rp[0] (always in-bounds) and their values zeroed at compute time.
    const int offL = lok ? -4 : 0;        // byte offset of left halo
    const int offR = rok ? 16 : 0;        // byte offset of right halo

    f32x4 m[NROWS];
    float hl[NROWS], hr[NROWS];

    // Pure load-issue for row-slot i (row r = h0-1+i). No selects here so the
    // issue segment stays loads-only and forces no early waitcnt.
    auto issue = [&](int i) {
        const int r  = h0 - 1 + i;                       // block-uniform
        const int rc = r < 0 ? 0 : (r >= IMG_H ? IMG_H - 1 : r);  // clamped
        const float* rp = xp + (size_t)rc * IMG_W + w0;
        m[i]  = *(const f32x4*)rp;
        hl[i] = *(const float*)((const char*)rp + offL);
        hr[i] = *(const float*)((const char*)rp + offR);
    };

    // ---- prologue: put PF rows in flight ----
#pragma unroll
    for (int i = 0; i < PF; ++i) issue(i);
    __builtin_amdgcn_sched_barrier(0);

    // ---- steady state: issue row i+PF, compute row i, store row i-2 ----
    float hE[3][4], hVE[3][4];
#pragma unroll
    for (int i = 0; i < NROWS; ++i) {
        if (i + PF < NROWS) issue(i + PF);
        // loads above must stay above the compute below (issue order = program order)
        __builtin_amdgcn_sched_barrier(0);

        const int r  = h0 - 1 + i;
        const bool rv = (r >= 0) && (r < IMG_H);         // block-uniform
        const int s = i % 3;

        f32x4 mm = m[i];
        float hlv = (rv && lok) ? hl[i] : 0.f;           // 0 -> e=1, ve=0 (pad)
        float hrv = (rv && rok) ? hr[i] : 0.f;
        if (!rv) mm = (f32x4){0.f, 0.f, 0.f, 0.f};

        const float eL = __expf(-hlv),  vL = hlv * eL;
        const float e0 = __expf(-mm.x), v0 = mm.x * e0;
        const float e1 = __expf(-mm.y), v1 = mm.y * e1;
        const float e2 = __expf(-mm.z), v2 = mm.z * e2;
        const float e3 = __expf(-mm.w), v3 = mm.w * e3;
        const float eR = __expf(-hrv),  vR = hrv * eR;
        hE[s][0] = eL + e0 + e1;  hVE[s][0] = vL + v0 + v1;
        hE[s][1] = e0 + e1 + e2;  hVE[s][1] = v0 + v1 + v2;
        hE[s][2] = e1 + e2 + e3;  hVE[s][2] = v1 + v2 + v3;
        hE[s][3] = e2 + e3 + eR;  hVE[s][3] = v2 + v3 + vR;

        if (i >= 2) {
            const int ro = h0 + i - 2;                   // output row
            f32x4 o;
#pragma unroll
            for (int p = 0; p < 4; ++p) {
                const float den = hE[0][p] + hE[1][p] + hE[2][p];
                const float num = hVE[0][p] + hVE[1][p] + hVE[2][p];
                o[p] = __fdividef(num, den);
            }
            // write-once output: nontemporal so it doesn't evict input from L2/L3
            __builtin_nontemporal_store(o, (f32x4*)(op + (size_t)ro * IMG_W + w0));
        }
    }
}

extern "C" void kernel_launch(void* const* d_in, const int* in_sizes, int n_in,
                              void* d_out, int out_size, void* d_ws, size_t ws_size,
                              hipStream_t stream) {
    const float* x = (const float*)d_in[0];
    float* out = (float*)d_out;
    dim3 grid(IMG_W / (128 * 4), IMG_H / RPB, NIMG);   // (3, 48, 16)
    dim3 block(128, 1, 1);
    WeightedAverage_55551107006568_kernel<<<grid, block, 0, stream>>>(x, out);
}